// Round 6
// baseline (2406.109 us; speedup 1.0000x reference)
//
#include <hip/hip_runtime.h>
#include <math.h>

static constexpr int Bn  = 64;    // batch
static constexpr int Cc  = 192;   // channels
static constexpr int Nn  = 784;   // H*W
static constexpr int C2c = 384;   // 2C
static constexpr int Kk  = 9;     // knn K

// ===========================================================================
// INDEX PATH — np-f32 bit-exact where values matter (fc1, norm, refine).
// Fast fmaf filter is allowed because refine re-ranks candidates exactly.
// ===========================================================================

// fc1_np: xt[b,o,n] = BN1( einsum_naive + bias ), numpy-f32-exact (no FMA,
// ascending-c accumulation).
__global__ __launch_bounds__(256) void fc1_np(
    const float* __restrict__ x, const float* __restrict__ w,
    const float* __restrict__ bias,
    const float* __restrict__ gg, const float* __restrict__ bb_,
    const float* __restrict__ mm, const float* __restrict__ vv,
    float* __restrict__ xt)
{
    __shared__ float As[16][64];
    __shared__ float Bs[16][64];
    const int b   = blockIdx.z;
    const int n0  = blockIdx.x * 64;
    const int o0  = blockIdx.y * 64;
    const int tid = threadIdx.x;
    const int tx = tid & 15, ty = tid >> 4;
    const int lo = tid & 63, lk4 = tid >> 6;
    const int ln4 = tid & 15, lbk = tid >> 4;
    const float* xb = x + (size_t)b * Cc * Nn;

    float acc[4][4];
#pragma unroll
    for (int i = 0; i < 4; ++i)
#pragma unroll
        for (int j = 0; j < 4; ++j) acc[i][j] = 0.f;

    for (int kt = 0; kt < 12; ++kt) {               // c ascending: kt*16 + kk
        const int k0 = kt * 16;
        float4 av = *reinterpret_cast<const float4*>(&w[(size_t)(o0 + lo) * 192 + k0 + lk4 * 4]);
        As[lk4*4+0][lo] = av.x;
        As[lk4*4+1][lo] = av.y;
        As[lk4*4+2][lo] = av.z;
        As[lk4*4+3][lo] = av.w;
        const int n = n0 + ln4 * 4;
        float4 bv = make_float4(0.f, 0.f, 0.f, 0.f);
        if (n < Nn) bv = *reinterpret_cast<const float4*>(&xb[(size_t)(k0 + lbk) * Nn + n]);
        *reinterpret_cast<float4*>(&Bs[lbk][ln4*4]) = bv;
        __syncthreads();
#pragma unroll
        for (int kk = 0; kk < 16; ++kk) {
            float ar[4], br[4];
#pragma unroll
            for (int i = 0; i < 4; ++i) ar[i] = As[kk][ty*4+i];
#pragma unroll
            for (int j = 0; j < 4; ++j) br[j] = Bs[kk][tx*4+j];
#pragma unroll
            for (int i = 0; i < 4; ++i)
#pragma unroll
                for (int j = 0; j < 4; ++j)
                    acc[i][j] = __fadd_rn(acc[i][j], __fmul_rn(ar[i], br[j]));
        }
        __syncthreads();
    }
    const int n = n0 + tx * 4;
    if (n < Nn) {
#pragma unroll
        for (int i = 0; i < 4; ++i) {
            const int o = o0 + ty * 4 + i;
            const float e  = __fadd_rn(vv[o], 1e-5f);
            const float r1 = __fsqrt_rn(e);
            const float rr = __fdiv_rn(1.f, r1);
            const float s  = __fmul_rn(gg[o], rr);
#pragma unroll
            for (int j = 0; j < 4; ++j) {
                const float h = __fadd_rn(acc[i][j], bias[o]);
                const float t = __fsub_rn(h, mm[o]);
                const float u = __fmul_rn(t, s);
                xt[((size_t)b * Cc + o) * Nn + n + j] = __fadd_rn(u, bb_[o]);
            }
        }
    }
}

// norm_np: numpy-exact. nrm = max(sqrt(seq-sum xt^2),1e-12); xn = xt/nrm;
// sq = numpy-pairwise sum (96+96 split, 8-way unroll, fixed combine tree).
__global__ __launch_bounds__(256) void norm_np(
    const float* __restrict__ xt, float* __restrict__ xn, float* __restrict__ sq)
{
    const int idx = blockIdx.x * 256 + threadIdx.x;
    if (idx >= Bn * Nn) return;
    const int n = idx % Nn;
    const int b = idx / Nn;
    const float* p = xt + (size_t)b * Cc * Nn + n;

    float acc = 0.f;
    for (int c = 0; c < Cc; ++c) {
        const float v = p[(size_t)c * Nn];
        acc = __fadd_rn(acc, __fmul_rn(v, v));
    }
    float nrm = __fsqrt_rn(acc);
    nrm = fmaxf(nrm, 1e-12f);

    float* q = xn + (size_t)b * Cc * Nn + n;
    for (int c = 0; c < Cc; ++c)
        q[(size_t)c * Nn] = __fdiv_rn(p[(size_t)c * Nn], nrm);

    float sblk[2];
#pragma unroll
    for (int blk = 0; blk < 2; ++blk) {
        const int base = blk * 96;
        float r[8];
#pragma unroll
        for (int j = 0; j < 8; ++j) {
            const float xv = __fdiv_rn(p[(size_t)(base + j) * Nn], nrm);
            r[j] = __fmul_rn(xv, xv);
        }
        for (int i = 8; i < 96; i += 8) {
#pragma unroll
            for (int j = 0; j < 8; ++j) {
                const float xv = __fdiv_rn(p[(size_t)(base + i + j) * Nn], nrm);
                r[j] = __fadd_rn(r[j], __fmul_rn(xv, xv));
            }
        }
        sblk[blk] = __fadd_rn(__fadd_rn(__fadd_rn(r[0], r[1]), __fadd_rn(r[2], r[3])),
                              __fadd_rn(__fadd_rn(r[4], r[5]), __fadd_rn(r[6], r[7])));
    }
    sq[idx] = __fadd_rn(sblk[0], sblk[1]);
}

// knn_fast16: FAST filter (fmaf ok). Per row: top-16 candidates by
// d = sqR + sqM - 2*dot. 64x64x16 GEMM sweep; per-thread top-16 over its
// 16-col slice; LDS merge to 16 per row. LDS ~33KB -> 4 blocks/CU.
__global__ __launch_bounds__(256) void knn_fast16(
    const float* __restrict__ xn, const float* __restrict__ sq,
    int* __restrict__ cand)
{
    __shared__ float As[16][64];
    __shared__ float Bs[16][64];
    __shared__ float UnionF[64 * 65];          // Ds[64][65], later Md[64*64]
    __shared__ unsigned short Mi16[64 * 64];
    __shared__ float sqR[64], sqM[64];

    float (*Ds)[65] = reinterpret_cast<float (*)[65]>(UnionF);

    const int b   = blockIdx.y;
    const int r0  = blockIdx.x * 64;
    const int tid = threadIdx.x;
    const int tx = tid & 15, ty = tid >> 4;
    const int lo = tid & 63, lk4 = tid >> 6;
    const int rr_t = tid >> 2, q_t = tid & 3;
    const float* xb  = xn + (size_t)b * Cc * Nn;
    const float* sqb = sq + (size_t)b * Nn;

    if (tid < 64) sqR[tid] = (r0 + tid < Nn) ? sqb[r0 + tid] : 0.f;

    float d16[16];
    int   i16[16];
#pragma unroll
    for (int k = 0; k < 16; ++k) { d16[k] = INFINITY; i16[k] = 0x7fffffff; }

    for (int mt = 0; mt < 13; ++mt) {
        const int m0 = mt * 64;
        __syncthreads();
        if (tid < 64) sqM[tid] = (m0 + tid < Nn) ? sqb[m0 + tid] : 0.f;

        float acc[4][4];
#pragma unroll
        for (int i = 0; i < 4; ++i)
#pragma unroll
            for (int j = 0; j < 4; ++j) acc[i][j] = 0.f;

        for (int kt = 0; kt < 12; ++kt) {
            const int k0 = kt * 16;
            const int r = r0 + lo;
            const int m = m0 + lo;
#pragma unroll
            for (int j = 0; j < 4; ++j) {
                const int kc = k0 + lk4 * 4 + j;
                As[lk4*4+j][lo] = (r < Nn) ? xb[(size_t)kc * Nn + r] : 0.f;
                Bs[lk4*4+j][lo] = (m < Nn) ? xb[(size_t)kc * Nn + m] : 0.f;
            }
            __syncthreads();
#pragma unroll
            for (int kk = 0; kk < 16; ++kk) {
                float4 a  = *reinterpret_cast<const float4*>(&As[kk][ty*4]);
                float4 bq = *reinterpret_cast<const float4*>(&Bs[kk][tx*4]);
                float ar[4] = {a.x, a.y, a.z, a.w};
                float br[4] = {bq.x, bq.y, bq.z, bq.w};
#pragma unroll
                for (int i = 0; i < 4; ++i)
#pragma unroll
                    for (int j = 0; j < 4; ++j)
                        acc[i][j] = fmaf(ar[i], br[j], acc[i][j]);
            }
            __syncthreads();
        }
#pragma unroll
        for (int i = 0; i < 4; ++i)
#pragma unroll
            for (int j = 0; j < 4; ++j) {
                const int rr = ty * 4 + i, cm = tx * 4 + j;
                const bool valid = (r0 + rr < Nn) && (m0 + cm < Nn);
                Ds[rr][cm] = valid ? (sqR[rr] + sqM[cm] - 2.f * acc[i][j]) : INFINITY;
            }
        __syncthreads();
#pragma unroll
        for (int c = 0; c < 16; ++c) {
            const float candv = Ds[rr_t][q_t * 16 + c];
            if (candv < d16[15]) {
                float v = candv; int vi = m0 + q_t * 16 + c;
#pragma unroll
                for (int k = 0; k < 16; ++k) {
                    if (v < d16[k]) {
                        float td = d16[k]; d16[k] = v; v = td;
                        int ti = i16[k]; i16[k] = vi; vi = ti;
                    }
                }
            }
        }
    }
    __syncthreads();                 // Ds dead; reuse as Md
    float* Md = UnionF;              // [64 rows][64 entries]
    {
        const int base = rr_t * 64 + q_t * 16;
#pragma unroll
        for (int k = 0; k < 16; ++k) {
            Md[base + k]  = d16[k];
            Mi16[base + k] = (unsigned short)i16[k];
        }
    }
    __syncthreads();
    if (tid < 64) {
        const int r = r0 + tid;
        if (r < Nn) {
            const int mb = tid * 64;
            int* op = cand + ((size_t)b * Nn + r) * 16;
            for (int k = 0; k < 16; ++k) {
                float bd = INFINITY; int bi = 0x7fffffff; int bp = 0;
                for (int j = 0; j < 64; ++j) {
                    const float dj = Md[mb + j];
                    const int   ij = (int)Mi16[mb + j];
                    if (dj < bd || (dj == bd && ij < bi)) { bd = dj; bi = ij; bp = j; }
                }
                Md[mb + bp] = INFINITY;
                op[k] = bi;
            }
        }
    }
}

// refine_np: EXACT np-f32 re-ranking of the 16 candidates per row.
// dot = sequential ascending-c rn(add, mul); d = rn(rn(sq_r - rn(2*dot)) + sq_m).
// Block = 16 rows x 16 candidate slots. Top-9 by (d, idx) lexicographic.
__global__ __launch_bounds__(256) void refine_np(
    const float* __restrict__ xn, const float* __restrict__ sq,
    const int* __restrict__ cand, int* __restrict__ nnidx)
{
    __shared__ float Dd[16][16];
    __shared__ int   Dm[16][16];
    const int b  = blockIdx.y;
    const int rl = threadIdx.x >> 4;
    const int k  = threadIdx.x & 15;
    const int r  = blockIdx.x * 16 + rl;
    const float* xb  = xn + (size_t)b * Cc * Nn;
    const float* sqb = sq + (size_t)b * Nn;

    const int m = cand[((size_t)b * Nn + r) * 16 + k];
    float dot = 0.f;
    const float* pr = xb + r;
    const float* pm = xb + m;
    for (int c = 0; c < Cc; ++c)
        dot = __fadd_rn(dot, __fmul_rn(pr[(size_t)c * Nn], pm[(size_t)c * Nn]));
    const float t1 = __fmul_rn(2.f, dot);
    const float t2 = __fsub_rn(sqb[r], t1);
    Dd[rl][k] = __fadd_rn(t2, sqb[m]);
    Dm[rl][k] = m;
    __syncthreads();

    if (k == 0) {
        float dl[16]; int il[16];
#pragma unroll
        for (int j = 0; j < 16; ++j) { dl[j] = Dd[rl][j]; il[j] = Dm[rl][j]; }
        int* op = nnidx + ((size_t)b * Nn + r) * Kk;
        for (int kk = 0; kk < Kk; ++kk) {
            int best = kk;
            for (int j = kk + 1; j < 16; ++j)
                if (dl[j] < dl[best] || (dl[j] == dl[best] && il[j] < il[best])) best = j;
            float td = dl[kk]; dl[kk] = dl[best]; dl[best] = td;
            int ti = il[kk]; il[kk] = il[best]; il[best] = ti;
            op[kk] = il[kk];
        }
    }
}

// ===========================================================================
// VALUE PATH — fast f32 (fmaf ok; error ~1e-5 << threshold 0.14)
// ===========================================================================

__global__ __launch_bounds__(256) void mr_naive(
    const float* __restrict__ xt, const int* __restrict__ nnidx,
    float* __restrict__ st)
{
    const long long idx = (long long)blockIdx.x * 256 + threadIdx.x;
    if (idx >= (long long)Bn * Cc * Nn) return;
    const int n = (int)(idx % Nn);
    const int c = (int)((idx / Nn) % Cc);
    const int b = (int)(idx / ((long long)Cc * Nn));
    const float* row = xt + ((size_t)b * Cc + c) * Nn;
    const float ctr = row[n];
    const int* ip = nnidx + ((size_t)b * Nn + n) * Kk;
    float mx = -INFINITY;
    for (int k = 0; k < Kk; ++k) {
        const float v = __fsub_rn(row[ip[k]], ctr);
        if (v > mx) mx = v;
    }
    st[((size_t)b * C2c + 2 * c) * Nn + n]     = ctr;
    st[((size_t)b * C2c + 2 * c + 1) * Nn + n] = mx;
}

__global__ __launch_bounds__(256) void gconv_kernel(
    const float* __restrict__ st, const float* __restrict__ gw,
    const float* __restrict__ gb,
    const float* __restrict__ gg, const float* __restrict__ bb_,
    const float* __restrict__ mm, const float* __restrict__ vv,
    float* __restrict__ out)
{
    __shared__ float As[16][32];
    __shared__ float Bs[16][64];
    const int b   = blockIdx.z;
    const int n0  = blockIdx.x * 64;
    const int grp = blockIdx.y / 3;
    const int o0  = (blockIdx.y % 3) * 32;
    const int tid = threadIdx.x;
    const int tx = tid & 15, ty = tid >> 4;
    const int lo = tid & 31, lk2 = tid >> 5;
    const int ln4 = tid & 15, lbk = tid >> 4;
    const float* stb = st + (size_t)b * C2c * Nn + (size_t)grp * 96 * Nn;
    const float* wgp = gw + (size_t)grp * 96 * 96;

    float acc[2][4];
#pragma unroll
    for (int i = 0; i < 2; ++i)
#pragma unroll
        for (int j = 0; j < 4; ++j) acc[i][j] = 0.f;

    for (int kt = 0; kt < 6; ++kt) {
        const int k0 = kt * 16;
        float2 av = *reinterpret_cast<const float2*>(&wgp[(size_t)(o0 + lo) * 96 + k0 + lk2 * 2]);
        As[lk2*2+0][lo] = av.x;
        As[lk2*2+1][lo] = av.y;
        const int n = n0 + ln4 * 4;
        float4 bv = make_float4(0.f, 0.f, 0.f, 0.f);
        if (n < Nn) bv = *reinterpret_cast<const float4*>(&stb[(size_t)(k0 + lbk) * Nn + n]);
        *reinterpret_cast<float4*>(&Bs[lbk][ln4*4]) = bv;
        __syncthreads();
#pragma unroll
        for (int kk = 0; kk < 16; ++kk) {
            float2 a  = *reinterpret_cast<const float2*>(&As[kk][ty*2]);
            float4 bq = *reinterpret_cast<const float4*>(&Bs[kk][tx*4]);
            float ar[2] = {a.x, a.y};
            float br[4] = {bq.x, bq.y, bq.z, bq.w};
#pragma unroll
            for (int i = 0; i < 2; ++i)
#pragma unroll
                for (int j = 0; j < 4; ++j)
                    acc[i][j] = fmaf(ar[i], br[j], acc[i][j]);
        }
        __syncthreads();
    }
    const int n = n0 + tx * 4;
    if (n < Nn) {
#pragma unroll
        for (int i = 0; i < 2; ++i) {
            const int oc = grp * 96 + o0 + ty * 2 + i;
            const float s  = gg[oc] * rsqrtf(vv[oc] + 1e-5f);
            const float sh = (gb[oc] - mm[oc]) * s + bb_[oc];
            float r[4];
#pragma unroll
            for (int j = 0; j < 4; ++j) {
                float v = fmaf(acc[i][j], s, sh);
                r[j] = 0.5f * v * (1.f + erff(v * 0.70710678118654752f));
            }
            float4 rv = make_float4(r[0], r[1], r[2], r[3]);
            *reinterpret_cast<float4*>(&out[((size_t)b * C2c + oc) * Nn + n]) = rv;
        }
    }
}

__global__ __launch_bounds__(256) void fc2_kernel(
    const float* __restrict__ gin, const float* __restrict__ w,
    const float* __restrict__ bias,
    const float* __restrict__ gg, const float* __restrict__ bb_,
    const float* __restrict__ mm, const float* __restrict__ vv,
    const float* __restrict__ xres,
    float* __restrict__ out)
{
    __shared__ float As[16][64];
    __shared__ float Bs[16][64];
    const int b   = blockIdx.z;
    const int n0  = blockIdx.x * 64;
    const int o0  = blockIdx.y * 64;
    const int tid = threadIdx.x;
    const int tx = tid & 15, ty = tid >> 4;
    const int lo = tid & 63, lk4 = tid >> 6;
    const int ln4 = tid & 15, lbk = tid >> 4;
    const float* gbp = gin + (size_t)b * C2c * Nn;
    const float* xb  = xres + (size_t)b * Cc * Nn;

    float acc[4][4];
#pragma unroll
    for (int i = 0; i < 4; ++i)
#pragma unroll
        for (int j = 0; j < 4; ++j) acc[i][j] = 0.f;

    for (int kt = 0; kt < 24; ++kt) {
        const int k0 = kt * 16;
        float4 av = *reinterpret_cast<const float4*>(&w[(size_t)(o0 + lo) * 384 + k0 + lk4 * 4]);
        As[lk4*4+0][lo] = av.x;
        As[lk4*4+1][lo] = av.y;
        As[lk4*4+2][lo] = av.z;
        As[lk4*4+3][lo] = av.w;
        const int n = n0 + ln4 * 4;
        float4 bv = make_float4(0.f, 0.f, 0.f, 0.f);
        if (n < Nn) bv = *reinterpret_cast<const float4*>(&gbp[(size_t)(k0 + lbk) * Nn + n]);
        *reinterpret_cast<float4*>(&Bs[lbk][ln4*4]) = bv;
        __syncthreads();
#pragma unroll
        for (int kk = 0; kk < 16; ++kk) {
            float4 a  = *reinterpret_cast<const float4*>(&As[kk][ty*4]);
            float4 bq = *reinterpret_cast<const float4*>(&Bs[kk][tx*4]);
            float ar[4] = {a.x, a.y, a.z, a.w};
            float br[4] = {bq.x, bq.y, bq.z, bq.w};
#pragma unroll
            for (int i = 0; i < 4; ++i)
#pragma unroll
                for (int j = 0; j < 4; ++j)
                    acc[i][j] = fmaf(ar[i], br[j], acc[i][j]);
        }
        __syncthreads();
    }
    const int n = n0 + tx * 4;
    if (n < Nn) {
#pragma unroll
        for (int i = 0; i < 4; ++i) {
            const int o = o0 + ty * 4 + i;
            const float s  = gg[o] * rsqrtf(vv[o] + 1e-5f);
            const float sh = (bias[o] - mm[o]) * s + bb_[o];
            float4 xr = *reinterpret_cast<const float4*>(&xb[(size_t)o * Nn + n]);
            float4 r;
            r.x = fmaf(acc[i][0], s, sh) + xr.x;
            r.y = fmaf(acc[i][1], s, sh) + xr.y;
            r.z = fmaf(acc[i][2], s, sh) + xr.z;
            r.w = fmaf(acc[i][3], s, sh) + xr.w;
            *reinterpret_cast<float4*>(&out[((size_t)b * Cc + o) * Nn + n]) = r;
        }
    }
}

// ---------------------------------------------------------------------------
extern "C" void kernel_launch(void* const* d_in, const int* in_sizes, int n_in,
                              void* d_out, int out_size, void* d_ws, size_t ws_size,
                              hipStream_t stream)
{
    const float* x     = (const float*)d_in[0];
    const float* fc1_w = (const float*)d_in[1];
    const float* fc1_b = (const float*)d_in[2];
    const float* bn1_g = (const float*)d_in[3];
    const float* bn1_b = (const float*)d_in[4];
    const float* bn1_m = (const float*)d_in[5];
    const float* bn1_v = (const float*)d_in[6];
    const float* gc_w  = (const float*)d_in[7];
    const float* gc_b  = (const float*)d_in[8];
    const float* bn2_g = (const float*)d_in[9];
    const float* bn2_b = (const float*)d_in[10];
    const float* bn2_m = (const float*)d_in[11];
    const float* bn2_v = (const float*)d_in[12];
    const float* fc2_w = (const float*)d_in[13];
    const float* fc2_b = (const float*)d_in[14];
    const float* bn3_g = (const float*)d_in[15];
    const float* bn3_b = (const float*)d_in[16];
    const float* bn3_m = (const float*)d_in[17];
    const float* bn3_v = (const float*)d_in[18];

    float* out = (float*)d_out;                  // xt scratch, overwritten by fc2

    // workspace (156 MB, same as round 5):
    // region A [0, 77MB):   st
    // region B [77,154MB):  xn | sq | cand16 (die after refine) -> gbuf
    // region C [154MB,+):   nnidx
    char* wsb = (char*)d_ws;
    const size_t regionBytes = (size_t)Bn * C2c * Nn * 4;   // 77,070,336
    float* st   = (float*)wsb;
    char*  g2   = wsb + regionBytes;
    float* xnb  = (float*)g2;                                 // 38,535,168 B
    float* sqb  = (float*)(g2 + (size_t)Bn * Cc * Nn * 4);    // 200,704 B
    int*   c16  = (int*)(g2 + (size_t)Bn * Cc * Nn * 4 + 200704);  // 3,211,264 B
    float* gbuf = (float*)g2;                                 // clobbers head (dead)
    int*   nni  = (int*)(wsb + 2 * regionBytes);

    const long long nBCN = (long long)Bn * Cc * Nn;
    const int nBN = Bn * Nn;

    dim3 blk(256);
    fc1_np<<<dim3(13, 3, Bn), blk, 0, stream>>>(
        x, fc1_w, fc1_b, bn1_g, bn1_b, bn1_m, bn1_v, out);
    norm_np<<<dim3((nBN + 255) / 256), blk, 0, stream>>>(out, xnb, sqb);
    knn_fast16<<<dim3(13, Bn), blk, 0, stream>>>(xnb, sqb, c16);
    refine_np<<<dim3(49, Bn), blk, 0, stream>>>(xnb, sqb, c16, nni);
    mr_naive<<<dim3((unsigned)((nBCN + 255) / 256)), blk, 0, stream>>>(out, nni, st);
    gconv_kernel<<<dim3(13, 12, Bn), blk, 0, stream>>>(
        st, gc_w, gc_b, bn2_g, bn2_b, bn2_m, bn2_v, gbuf);
    fc2_kernel<<<dim3(13, 3, Bn), blk, 0, stream>>>(
        gbuf, fc2_w, fc2_b, bn3_g, bn3_b, bn3_m, bn3_v, x, out);
}

// Round 7
// 1128.522 us; speedup vs baseline: 2.1321x; 2.1321x over previous
//
#include <hip/hip_runtime.h>
#include <math.h>

static constexpr int Bn  = 64;    // batch
static constexpr int Cc  = 192;   // channels
static constexpr int Nn  = 784;   // H*W
static constexpr int C2c = 384;   // 2C
static constexpr int Kk  = 9;     // knn K

// ===========================================================================
// INDEX PATH — np-f32 bit-exact where values matter (fc1, norm, refine).
// Fast filter (dist_gemm + select16) only proposes candidates; refine_np
// re-ranks them with bit-exact np arithmetic.
// ===========================================================================

// fc1_np: xt[b,o,n] = BN1( einsum_naive + bias ), numpy-f32-exact (no FMA,
// ascending-c accumulation). BIT-CRITICAL — do not alter arithmetic.
__global__ __launch_bounds__(256) void fc1_np(
    const float* __restrict__ x, const float* __restrict__ w,
    const float* __restrict__ bias,
    const float* __restrict__ gg, const float* __restrict__ bb_,
    const float* __restrict__ mm, const float* __restrict__ vv,
    float* __restrict__ xt)
{
    __shared__ float As[16][64];
    __shared__ float Bs[16][64];
    const int b   = blockIdx.z;
    const int n0  = blockIdx.x * 64;
    const int o0  = blockIdx.y * 64;
    const int tid = threadIdx.x;
    const int tx = tid & 15, ty = tid >> 4;
    const int lo = tid & 63, lk4 = tid >> 6;
    const int ln4 = tid & 15, lbk = tid >> 4;
    const float* xb = x + (size_t)b * Cc * Nn;

    float acc[4][4];
#pragma unroll
    for (int i = 0; i < 4; ++i)
#pragma unroll
        for (int j = 0; j < 4; ++j) acc[i][j] = 0.f;

    for (int kt = 0; kt < 12; ++kt) {               // c ascending: kt*16 + kk
        const int k0 = kt * 16;
        float4 av = *reinterpret_cast<const float4*>(&w[(size_t)(o0 + lo) * 192 + k0 + lk4 * 4]);
        As[lk4*4+0][lo] = av.x;
        As[lk4*4+1][lo] = av.y;
        As[lk4*4+2][lo] = av.z;
        As[lk4*4+3][lo] = av.w;
        const int n = n0 + ln4 * 4;
        float4 bv = make_float4(0.f, 0.f, 0.f, 0.f);
        if (n < Nn) bv = *reinterpret_cast<const float4*>(&xb[(size_t)(k0 + lbk) * Nn + n]);
        *reinterpret_cast<float4*>(&Bs[lbk][ln4*4]) = bv;
        __syncthreads();
#pragma unroll
        for (int kk = 0; kk < 16; ++kk) {
            float ar[4], br[4];
#pragma unroll
            for (int i = 0; i < 4; ++i) ar[i] = As[kk][ty*4+i];
#pragma unroll
            for (int j = 0; j < 4; ++j) br[j] = Bs[kk][tx*4+j];
#pragma unroll
            for (int i = 0; i < 4; ++i)
#pragma unroll
                for (int j = 0; j < 4; ++j)
                    acc[i][j] = __fadd_rn(acc[i][j], __fmul_rn(ar[i], br[j]));
        }
        __syncthreads();
    }
    const int n = n0 + tx * 4;
    if (n < Nn) {
#pragma unroll
        for (int i = 0; i < 4; ++i) {
            const int o = o0 + ty * 4 + i;
            const float e  = __fadd_rn(vv[o], 1e-5f);
            const float r1 = __fsqrt_rn(e);
            const float rr = __fdiv_rn(1.f, r1);
            const float s  = __fmul_rn(gg[o], rr);
#pragma unroll
            for (int j = 0; j < 4; ++j) {
                const float h = __fadd_rn(acc[i][j], bias[o]);
                const float t = __fsub_rn(h, mm[o]);
                const float u = __fmul_rn(t, s);
                xt[((size_t)b * Cc + o) * Nn + n + j] = __fadd_rn(u, bb_[o]);
            }
        }
    }
}

// norm_np: numpy-exact. BIT-CRITICAL.
__global__ __launch_bounds__(256) void norm_np(
    const float* __restrict__ xt, float* __restrict__ xn, float* __restrict__ sq)
{
    const int idx = blockIdx.x * 256 + threadIdx.x;
    if (idx >= Bn * Nn) return;
    const int n = idx % Nn;
    const int b = idx / Nn;
    const float* p = xt + (size_t)b * Cc * Nn + n;

    float acc = 0.f;
    for (int c = 0; c < Cc; ++c) {
        const float v = p[(size_t)c * Nn];
        acc = __fadd_rn(acc, __fmul_rn(v, v));
    }
    float nrm = __fsqrt_rn(acc);
    nrm = fmaxf(nrm, 1e-12f);

    float* q = xn + (size_t)b * Cc * Nn + n;
    for (int c = 0; c < Cc; ++c)
        q[(size_t)c * Nn] = __fdiv_rn(p[(size_t)c * Nn], nrm);

    float sblk[2];
#pragma unroll
    for (int blk = 0; blk < 2; ++blk) {
        const int base = blk * 96;
        float r[8];
#pragma unroll
        for (int j = 0; j < 8; ++j) {
            const float xv = __fdiv_rn(p[(size_t)(base + j) * Nn], nrm);
            r[j] = __fmul_rn(xv, xv);
        }
        for (int i = 8; i < 96; i += 8) {
#pragma unroll
            for (int j = 0; j < 8; ++j) {
                const float xv = __fdiv_rn(p[(size_t)(base + i + j) * Nn], nrm);
                r[j] = __fadd_rn(r[j], __fmul_rn(xv, xv));
            }
        }
        sblk[blk] = __fadd_rn(__fadd_rn(__fadd_rn(r[0], r[1]), __fadd_rn(r[2], r[3])),
                              __fadd_rn(__fadd_rn(r[4], r[5]), __fadd_rn(r[6], r[7])));
    }
    sq[idx] = __fadd_rn(sblk[0], sblk[1]);
}

// dist_gemm: FAST filter GEMM only — dist[b16][r][m] = -dot(xn_r, xn_m).
// One 64x64 tile per block, fmaf inner loop, register->global write.
__global__ __launch_bounds__(256) void dist_gemm(
    const float* __restrict__ xn, float* __restrict__ dist, int bchunk)
{
    __shared__ float As[16][64];
    __shared__ float Bs[16][64];
    const int bt = blockIdx.x;             // 0..168
    const int rt = bt / 13, mt = bt % 13;
    const int bc = blockIdx.y;             // 0..15
    const int b  = bchunk * 16 + bc;
    const int r0 = rt * 64, m0 = mt * 64;
    const int tid = threadIdx.x;
    const int tx = tid & 15, ty = tid >> 4;
    const int lo = tid & 63, lk4 = tid >> 6;
    const float* xb = xn + (size_t)b * Cc * Nn;

    float acc[4][4];
#pragma unroll
    for (int i = 0; i < 4; ++i)
#pragma unroll
        for (int j = 0; j < 4; ++j) acc[i][j] = 0.f;

    for (int kt = 0; kt < 12; ++kt) {
        const int k0 = kt * 16;
        const int r = r0 + lo, m = m0 + lo;
#pragma unroll
        for (int j = 0; j < 4; ++j) {
            const int kc = k0 + lk4 * 4 + j;
            As[lk4*4+j][lo] = (r < Nn) ? xb[(size_t)kc * Nn + r] : 0.f;
            Bs[lk4*4+j][lo] = (m < Nn) ? xb[(size_t)kc * Nn + m] : 0.f;
        }
        __syncthreads();
#pragma unroll
        for (int kk = 0; kk < 16; ++kk) {
            float4 a  = *reinterpret_cast<const float4*>(&As[kk][ty*4]);
            float4 bq = *reinterpret_cast<const float4*>(&Bs[kk][tx*4]);
            float ar[4] = {a.x, a.y, a.z, a.w};
            float br[4] = {bq.x, bq.y, bq.z, bq.w};
#pragma unroll
            for (int i = 0; i < 4; ++i)
#pragma unroll
                for (int j = 0; j < 4; ++j)
                    acc[i][j] = fmaf(ar[i], br[j], acc[i][j]);
        }
        __syncthreads();
    }
    float* db = dist + (size_t)bc * Nn * Nn;
    const int m = m0 + tx * 4;
    if (m + 3 < Nn) {
#pragma unroll
        for (int i = 0; i < 4; ++i) {
            const int r = r0 + ty * 4 + i;
            if (r < Nn) {
                float4 o = make_float4(-acc[i][0], -acc[i][1], -acc[i][2], -acc[i][3]);
                *reinterpret_cast<float4*>(&db[(size_t)r * Nn + m]) = o;
            }
        }
    }
}

// select16: one wave per row; 784 dists in 13 regs/lane; 16x argmin-extract
// via shfl_xor reduce (value, then lower-index tie-break). No LDS, no scratch.
__global__ __launch_bounds__(256) void select16(
    const float* __restrict__ dist, int* __restrict__ cand, int bchunk)
{
    const int wid = blockIdx.x * 4 + (threadIdx.x >> 6);   // wave id in chunk
    const int L   = threadIdx.x & 63;
    const int r   = wid % Nn;
    const int bc  = wid / Nn;
    const int b   = bchunk * 16 + bc;
    const float* drow = dist + ((size_t)bc * Nn + r) * Nn;

    float v[13];
#pragma unroll
    for (int s = 0; s < 12; ++s) v[s] = drow[s * 64 + L];
    v[12] = (L < 16) ? drow[768 + L] : INFINITY;

    float mv = v[0]; int ms = 0;
#pragma unroll
    for (int s = 1; s < 13; ++s)
        if (v[s] < mv) { mv = v[s]; ms = s; }

    int out[16];
#pragma unroll
    for (int k = 0; k < 16; ++k) {
        float gv = mv; int gi = ms * 64 + L;
#pragma unroll
        for (int off = 1; off < 64; off <<= 1) {
            const float ov = __shfl_xor(gv, off, 64);
            const int   oi = __shfl_xor(gi, off, 64);
            if (ov < gv || (ov == gv && oi < gi)) { gv = ov; gi = oi; }
        }
        out[k] = gi;
        const int ol = gi & 63, os = gi >> 6;
        if (L == ol) {
#pragma unroll
            for (int s = 0; s < 13; ++s) if (s == os) v[s] = INFINITY;
            mv = v[0]; ms = 0;
#pragma unroll
            for (int s = 1; s < 13; ++s)
                if (v[s] < mv) { mv = v[s]; ms = s; }
        }
    }
    if (L == 0) {
        int* op = cand + ((size_t)b * Nn + r) * 16;
#pragma unroll
        for (int k = 0; k < 16; ++k) op[k] = out[k];
    }
}

// refine_np: EXACT np-f32 re-ranking of the 16 candidates per row.
// BIT-CRITICAL arithmetic.
__global__ __launch_bounds__(256) void refine_np(
    const float* __restrict__ xn, const float* __restrict__ sq,
    const int* __restrict__ cand, int* __restrict__ nnidx)
{
    __shared__ float Dd[16][16];
    __shared__ int   Dm[16][16];
    const int b  = blockIdx.y;
    const int rl = threadIdx.x >> 4;
    const int k  = threadIdx.x & 15;
    const int r  = blockIdx.x * 16 + rl;
    const float* xb  = xn + (size_t)b * Cc * Nn;
    const float* sqb = sq + (size_t)b * Nn;

    const int m = cand[((size_t)b * Nn + r) * 16 + k];
    float dot = 0.f;
    const float* pr = xb + r;
    const float* pm = xb + m;
    for (int c = 0; c < Cc; ++c)
        dot = __fadd_rn(dot, __fmul_rn(pr[(size_t)c * Nn], pm[(size_t)c * Nn]));
    const float t1 = __fmul_rn(2.f, dot);
    const float t2 = __fsub_rn(sqb[r], t1);
    Dd[rl][k] = __fadd_rn(t2, sqb[m]);
    Dm[rl][k] = m;
    __syncthreads();

    if (k == 0) {
        float dl[16]; int il[16];
#pragma unroll
        for (int j = 0; j < 16; ++j) { dl[j] = Dd[rl][j]; il[j] = Dm[rl][j]; }
        int* op = nnidx + ((size_t)b * Nn + r) * Kk;
        for (int kk = 0; kk < Kk; ++kk) {
            int best = kk;
            for (int j = kk + 1; j < 16; ++j)
                if (dl[j] < dl[best] || (dl[j] == dl[best] && il[j] < il[best])) best = j;
            float td = dl[kk]; dl[kk] = dl[best]; dl[best] = td;
            int ti = il[kk]; il[kk] = il[best]; il[best] = ti;
            op[kk] = il[kk];
        }
    }
}

// ===========================================================================
// VALUE PATH — fast f32 (fmaf ok; error ~1e-5 << threshold 0.14)
// ===========================================================================

__global__ __launch_bounds__(256) void mr_naive(
    const float* __restrict__ xt, const int* __restrict__ nnidx,
    float* __restrict__ st)
{
    const long long idx = (long long)blockIdx.x * 256 + threadIdx.x;
    if (idx >= (long long)Bn * Cc * Nn) return;
    const int n = (int)(idx % Nn);
    const int c = (int)((idx / Nn) % Cc);
    const int b = (int)(idx / ((long long)Cc * Nn));
    const float* row = xt + ((size_t)b * Cc + c) * Nn;
    const float ctr = row[n];
    const int* ip = nnidx + ((size_t)b * Nn + n) * Kk;
    float mx = -INFINITY;
    for (int k = 0; k < Kk; ++k) {
        const float v = __fsub_rn(row[ip[k]], ctr);
        if (v > mx) mx = v;
    }
    st[((size_t)b * C2c + 2 * c) * Nn + n]     = ctr;
    st[((size_t)b * C2c + 2 * c + 1) * Nn + n] = mx;
}

__global__ __launch_bounds__(256) void gconv_kernel(
    const float* __restrict__ st, const float* __restrict__ gw,
    const float* __restrict__ gb,
    const float* __restrict__ gg, const float* __restrict__ bb_,
    const float* __restrict__ mm, const float* __restrict__ vv,
    float* __restrict__ out)
{
    __shared__ float As[16][32];
    __shared__ float Bs[16][64];
    const int b   = blockIdx.z;
    const int n0  = blockIdx.x * 64;
    const int grp = blockIdx.y / 3;
    const int o0  = (blockIdx.y % 3) * 32;
    const int tid = threadIdx.x;
    const int tx = tid & 15, ty = tid >> 4;
    const int lo = tid & 31, lk2 = tid >> 5;
    const int ln4 = tid & 15, lbk = tid >> 4;
    const float* stb = st + (size_t)b * C2c * Nn + (size_t)grp * 96 * Nn;
    const float* wgp = gw + (size_t)grp * 96 * 96;

    float acc[2][4];
#pragma unroll
    for (int i = 0; i < 2; ++i)
#pragma unroll
        for (int j = 0; j < 4; ++j) acc[i][j] = 0.f;

    for (int kt = 0; kt < 6; ++kt) {
        const int k0 = kt * 16;
        float2 av = *reinterpret_cast<const float2*>(&wgp[(size_t)(o0 + lo) * 96 + k0 + lk2 * 2]);
        As[lk2*2+0][lo] = av.x;
        As[lk2*2+1][lo] = av.y;
        const int n = n0 + ln4 * 4;
        float4 bv = make_float4(0.f, 0.f, 0.f, 0.f);
        if (n < Nn) bv = *reinterpret_cast<const float4*>(&stb[(size_t)(k0 + lbk) * Nn + n]);
        *reinterpret_cast<float4*>(&Bs[lbk][ln4*4]) = bv;
        __syncthreads();
#pragma unroll
        for (int kk = 0; kk < 16; ++kk) {
            float2 a  = *reinterpret_cast<const float2*>(&As[kk][ty*2]);
            float4 bq = *reinterpret_cast<const float4*>(&Bs[kk][tx*4]);
            float ar[2] = {a.x, a.y};
            float br[4] = {bq.x, bq.y, bq.z, bq.w};
#pragma unroll
            for (int i = 0; i < 2; ++i)
#pragma unroll
                for (int j = 0; j < 4; ++j)
                    acc[i][j] = fmaf(ar[i], br[j], acc[i][j]);
        }
        __syncthreads();
    }
    const int n = n0 + tx * 4;
    if (n < Nn) {
#pragma unroll
        for (int i = 0; i < 2; ++i) {
            const int oc = grp * 96 + o0 + ty * 2 + i;
            const float s  = gg[oc] * rsqrtf(vv[oc] + 1e-5f);
            const float sh = (gb[oc] - mm[oc]) * s + bb_[oc];
            float r[4];
#pragma unroll
            for (int j = 0; j < 4; ++j) {
                float v = fmaf(acc[i][j], s, sh);
                r[j] = 0.5f * v * (1.f + erff(v * 0.70710678118654752f));
            }
            float4 rv = make_float4(r[0], r[1], r[2], r[3]);
            *reinterpret_cast<float4*>(&out[((size_t)b * C2c + oc) * Nn + n]) = rv;
        }
    }
}

__global__ __launch_bounds__(256) void fc2_kernel(
    const float* __restrict__ gin, const float* __restrict__ w,
    const float* __restrict__ bias,
    const float* __restrict__ gg, const float* __restrict__ bb_,
    const float* __restrict__ mm, const float* __restrict__ vv,
    const float* __restrict__ xres,
    float* __restrict__ out)
{
    __shared__ float As[16][64];
    __shared__ float Bs[16][64];
    const int b   = blockIdx.z;
    const int n0  = blockIdx.x * 64;
    const int o0  = blockIdx.y * 64;
    const int tid = threadIdx.x;
    const int tx = tid & 15, ty = tid >> 4;
    const int lo = tid & 63, lk4 = tid >> 6;
    const int ln4 = tid & 15, lbk = tid >> 4;
    const float* gbp = gin + (size_t)b * C2c * Nn;
    const float* xb  = xres + (size_t)b * Cc * Nn;

    float acc[4][4];
#pragma unroll
    for (int i = 0; i < 4; ++i)
#pragma unroll
        for (int j = 0; j < 4; ++j) acc[i][j] = 0.f;

    for (int kt = 0; kt < 24; ++kt) {
        const int k0 = kt * 16;
        float4 av = *reinterpret_cast<const float4*>(&w[(size_t)(o0 + lo) * 384 + k0 + lk4 * 4]);
        As[lk4*4+0][lo] = av.x;
        As[lk4*4+1][lo] = av.y;
        As[lk4*4+2][lo] = av.z;
        As[lk4*4+3][lo] = av.w;
        const int n = n0 + ln4 * 4;
        float4 bv = make_float4(0.f, 0.f, 0.f, 0.f);
        if (n < Nn) bv = *reinterpret_cast<const float4*>(&gbp[(size_t)(k0 + lbk) * Nn + n]);
        *reinterpret_cast<float4*>(&Bs[lbk][ln4*4]) = bv;
        __syncthreads();
#pragma unroll
        for (int kk = 0; kk < 16; ++kk) {
            float4 a  = *reinterpret_cast<const float4*>(&As[kk][ty*4]);
            float4 bq = *reinterpret_cast<const float4*>(&Bs[kk][tx*4]);
            float ar[4] = {a.x, a.y, a.z, a.w};
            float br[4] = {bq.x, bq.y, bq.z, bq.w};
#pragma unroll
            for (int i = 0; i < 4; ++i)
#pragma unroll
                for (int j = 0; j < 4; ++j)
                    acc[i][j] = fmaf(ar[i], br[j], acc[i][j]);
        }
        __syncthreads();
    }
    const int n = n0 + tx * 4;
    if (n < Nn) {
#pragma unroll
        for (int i = 0; i < 4; ++i) {
            const int o = o0 + ty * 4 + i;
            const float s  = gg[o] * rsqrtf(vv[o] + 1e-5f);
            const float sh = (bias[o] - mm[o]) * s + bb_[o];
            float4 xr = *reinterpret_cast<const float4*>(&xb[(size_t)o * Nn + n]);
            float4 r;
            r.x = fmaf(acc[i][0], s, sh) + xr.x;
            r.y = fmaf(acc[i][1], s, sh) + xr.y;
            r.z = fmaf(acc[i][2], s, sh) + xr.z;
            r.w = fmaf(acc[i][3], s, sh) + xr.w;
            *reinterpret_cast<float4*>(&out[((size_t)b * Cc + o) * Nn + n]) = r;
        }
    }
}

// ---------------------------------------------------------------------------
extern "C" void kernel_launch(void* const* d_in, const int* in_sizes, int n_in,
                              void* d_out, int out_size, void* d_ws, size_t ws_size,
                              hipStream_t stream)
{
    const float* x     = (const float*)d_in[0];
    const float* fc1_w = (const float*)d_in[1];
    const float* fc1_b = (const float*)d_in[2];
    const float* bn1_g = (const float*)d_in[3];
    const float* bn1_b = (const float*)d_in[4];
    const float* bn1_m = (const float*)d_in[5];
    const float* bn1_v = (const float*)d_in[6];
    const float* gc_w  = (const float*)d_in[7];
    const float* gc_b  = (const float*)d_in[8];
    const float* bn2_g = (const float*)d_in[9];
    const float* bn2_b = (const float*)d_in[10];
    const float* bn2_m = (const float*)d_in[11];
    const float* bn2_v = (const float*)d_in[12];
    const float* fc2_w = (const float*)d_in[13];
    const float* fc2_b = (const float*)d_in[14];
    const float* bn3_g = (const float*)d_in[15];
    const float* bn3_b = (const float*)d_in[16];
    const float* bn3_m = (const float*)d_in[17];
    const float* bn3_v = (const float*)d_in[18];

    float* out = (float*)d_out;                  // xt scratch, overwritten by fc2

    // workspace (max concurrent 156 MB, same as proven rounds):
    //   [0, 77.07M):      dist16 (39.3M, chunked; dies after last select16)
    //                     -> st (born at mr)
    //   [77.07, 154.14M): xn | sq | cand16 (die after refine) -> gbuf
    //   [154.14M, +1.8M): nnidx
    char* wsb = (char*)d_ws;
    const size_t regionBytes = (size_t)Bn * C2c * Nn * 4;   // 77,070,336
    float* dist = (float*)wsb;
    float* st   = (float*)wsb;
    char*  g2   = wsb + regionBytes;
    float* xnb  = (float*)g2;                                      // 38,535,168 B
    float* sqb  = (float*)(g2 + (size_t)Bn * Cc * Nn * 4);         // 200,704 B
    int*   c16  = (int*)(g2 + (size_t)Bn * Cc * Nn * 4 + 200704);  // 3,211,264 B
    float* gbuf = (float*)g2;                                      // clobbers head (dead)
    int*   nni  = (int*)(wsb + 2 * regionBytes);

    const long long nBCN = (long long)Bn * Cc * Nn;
    const int nBN = Bn * Nn;

    dim3 blk(256);
    fc1_np<<<dim3(13, 3, Bn), blk, 0, stream>>>(
        x, fc1_w, fc1_b, bn1_g, bn1_b, bn1_m, bn1_v, out);
    norm_np<<<dim3((nBN + 255) / 256), blk, 0, stream>>>(out, xnb, sqb);
    for (int ch = 0; ch < 4; ++ch) {
        dist_gemm<<<dim3(169, 16), blk, 0, stream>>>(xnb, dist, ch);
        select16<<<dim3(16 * Nn / 4), blk, 0, stream>>>(dist, c16, ch);
    }
    refine_np<<<dim3(49, Bn), blk, 0, stream>>>(xnb, sqb, c16, nni);
    mr_naive<<<dim3((unsigned)((nBCN + 255) / 256)), blk, 0, stream>>>(out, nni, st);
    gconv_kernel<<<dim3(13, 12, Bn), blk, 0, stream>>>(
        st, gc_w, gc_b, bn2_g, bn2_b, bn2_m, bn2_v, gbuf);
    fc2_kernel<<<dim3(13, 3, Bn), blk, 0, stream>>>(
        gbuf, fc2_w, fc2_b, bn3_g, bn3_b, bn3_m, bn3_v, x, out);
}